// Round 16
// baseline (296.142 us; speedup 1.0000x reference)
//
#include <hip/hip_runtime.h>
#include <hip/hip_bf16.h>
#include <math.h>

// ws layout (floats): [0,458752) fp[64][14][512] conv partials;
//   [458752,458816) qacc; [458816,458880) qnorm; [458880,458944) fincnt(u32)
// fp8 e4m3 state (x256-scaled) ping-pong at byte offset 4MB: SA, SB (each 8.39MB)

typedef _Float16 h4 __attribute__((ext_vector_type(4)));
typedef _Float16 h8 __attribute__((ext_vector_type(8)));
typedef float f32x4 __attribute__((ext_vector_type(4)));
typedef float f2 __attribute__((ext_vector_type(2)));

__device__ __forceinline__ f2 mk2(float a, float b){ f2 r; r.x=a; r.y=b; return r; }
__device__ __forceinline__ f2 cmulf(f2 a, f2 b){
    return mk2(a.x*b.x - a.y*b.y, a.x*b.y + a.y*b.x);
}
__device__ __forceinline__ f2 cfma2(f2 g, f2 q, f2 acc){
    f2 qs = __builtin_shufflevector(q, q, 1, 0);
    acc += mk2(g.x, g.x) * q;
    acc += mk2(-g.y, g.y) * qs;
    return acc;
}
__device__ __forceinline__ void cswap(f2& a, f2& b){ f2 t=a; a=b; b=t; }
__device__ __forceinline__ unsigned pk2(f2 a){
    union{ _Float16 h[2]; unsigned u; } z;
    z.h[0] = (_Float16)a.x; z.h[1] = (_Float16)a.y; return z.u;
}
__device__ __forceinline__ f2 up2(unsigned u){
    union{ unsigned u; _Float16 h[2]; } z; z.u = u;
    return mk2((float)z.h[0], (float)z.h[1]);
}
__device__ __forceinline__ h8 cvt8(float4 a, float4 b){
    h8 r; r[0]=(_Float16)a.x; r[1]=(_Float16)a.y; r[2]=(_Float16)a.z; r[3]=(_Float16)a.w;
    r[4]=(_Float16)b.x; r[5]=(_Float16)b.y; r[6]=(_Float16)b.z; r[7]=(_Float16)b.w; return r;
}

// ---- fp8 e4m3 pack/unpack (OCP; gfx950 HW converts, manual fallback) ----
__device__ __forceinline__ unsigned enc1(float x){
    union{ _Float16 h; unsigned short u; } z; z.h = (_Float16)x;
    unsigned short h = z.u;
    unsigned s = (h>>8) & 0x80u;
    int mag = h & 0x7fff;
    if (mag < 0x2400) return s;
    mag -= 0x2000;
    int r = mag + 0x3F + ((mag>>7)&1);
    int v = r >> 7;
    if (v > 0x7E) v = 0x7E;
    return s | (unsigned)v;
}
__device__ __forceinline__ float dec1(unsigned b){
    unsigned mag = b & 0x7fu;
    if ((mag>>3) == 0) return 0.f;
    unsigned short h = (unsigned short)(((b&0x80u)<<8) | ((mag<<7) + 0x2000));
    union{ unsigned short u; _Float16 h2; } z; z.u = h; return (float)z.h2;
}
__device__ __forceinline__ unsigned pk8(f2 a, f2 b){
#if __has_builtin(__builtin_amdgcn_cvt_pk_fp8_f32)
    unsigned w = (unsigned)__builtin_amdgcn_cvt_pk_fp8_f32(a.x, a.y, 0, false);
    w = (unsigned)__builtin_amdgcn_cvt_pk_fp8_f32(b.x, b.y, (int)w, true);
    return w;
#else
    return enc1(a.x) | (enc1(a.y)<<8) | (enc1(b.x)<<16) | (enc1(b.y)<<24);
#endif
}
template<bool HI>
__device__ __forceinline__ f2 up8(unsigned u){
#if __has_builtin(__builtin_amdgcn_cvt_pk_f32_fp8)
    auto r = __builtin_amdgcn_cvt_pk_f32_fp8((int)u, HI);
    return mk2(r[0], r[1]);
#else
    unsigned b0 = HI ? ((u>>16)&0xffu) : (u&0xffu);
    unsigned b1 = HI ? (u>>24) : ((u>>8)&0xffu);
    return mk2(dec1(b0), dec1(b1));
#endif
}

// ---------------- conv + relu + partial global-avg-pool via MFMA ----------------
// DIAG: nrep repeats the full body (stage + MFMA + write); idempotent plain stores.
__global__ __launch_bounds__(512) void k_conv_mfma(const float* __restrict__ x,
            const float* __restrict__ Wc, const float* __restrict__ bc,
            float* __restrict__ fp, float* __restrict__ qacc,
            float* __restrict__ qnorm, unsigned* __restrict__ fincnt, int nrep){
    extern __shared__ _Float16 Al[];   // [224][72]
    const int tid = threadIdx.x;
    const int b = blockIdx.x / 14, seg = blockIdx.x % 14;
    for (int rep = 0; rep < nrep; ++rep){
    for (int idx = tid; idx < 2688; idx += 512){
        int cr = idx / 224, p = idx - cr*224;
        int cc = cr >> 2, r = cr & 3;
        int ro = p / 56, ow = p - ro*56;
        int ih = (seg*4 + ro)*4 + r;
        float4 v = *(const float4*)&x[(((size_t)b*3 + cc)*224 + ih)*224 + ow*4];
        h4 hv; hv[0]=(_Float16)v.x; hv[1]=(_Float16)v.y; hv[2]=(_Float16)v.z; hv[3]=(_Float16)v.w;
        *(h4*)&Al[p*72 + cr*4] = hv;
    }
    for (int idx = tid; idx < 896; idx += 512){
        int p = idx >> 2, j = idx & 3;
        *(h4*)&Al[p*72 + 48 + j*4] = (h4){0,0,0,0};
    }
    if (seg == 0 && tid == 0) qacc[b] = 0.f;
    if (seg == 0 && tid == 1) qnorm[b] = 0.f;
    if (seg == 0 && tid == 2) fincnt[b] = 0u;
    const int wv = tid >> 6, lane = tid & 63;
    const int col = lane & 15, kg = lane >> 4;
    const int n0 = wv * 64;
    const h8 hz = {0,0,0,0,0,0,0,0};
    h8 Bf[4], Bf2[4];
    float bias[4], pool[4];
    #pragma unroll
    for (int nt=0; nt<4; ++nt){
        int ch = n0 + nt*16 + col;
        const float* wr = &Wc[ch*48];
        float4 wa = *(const float4*)&wr[kg*8];
        float4 wb = *(const float4*)&wr[kg*8 + 4];
        Bf[nt] = cvt8(wa, wb);
        if (kg < 2){
            float4 wc4 = *(const float4*)&wr[32 + kg*8];
            float4 wd  = *(const float4*)&wr[36 + kg*8];
            Bf2[nt] = cvt8(wc4, wd);
        } else Bf2[nt] = hz;
        bias[nt] = bc[ch];
        pool[nt] = 0.f;
    }
    __syncthreads();
    #pragma unroll 2
    for (int mt=0; mt<14; ++mt){
        const _Float16* ar = &Al[(mt*16 + col)*72];
        h8 Af  = *(const h8*)&ar[kg*8];
        h8 Af2 = *(const h8*)&ar[32 + kg*8];
        #pragma unroll
        for (int nt=0; nt<4; ++nt){
            f32x4 acc = {0.f,0.f,0.f,0.f};
            acc = __builtin_amdgcn_mfma_f32_16x16x32_f16(Af,  Bf[nt],  acc, 0,0,0);
            acc = __builtin_amdgcn_mfma_f32_16x16x32_f16(Af2, Bf2[nt], acc, 0,0,0);
            #pragma unroll
            for (int j=0;j<4;++j) pool[nt] += fmaxf(acc[j] + bias[nt], 0.f);
        }
    }
    #pragma unroll
    for (int nt=0; nt<4; ++nt){
        pool[nt] += __shfl_xor(pool[nt], 16);
        pool[nt] += __shfl_xor(pool[nt], 32);
    }
    if (lane < 16){
        float* dst = &fp[((b*14 + seg)<<9) + n0 + lane];
        #pragma unroll
        for (int nt=0; nt<4; ++nt) dst[nt*16] = pool[nt];
    }
    __syncthreads();   // rep separation: writes/reads of Al done before restage
    }
}

// ---------------- VQC layer kernels ----------------
__device__ __forceinline__ int SW(int a){
    int h = ((a>>5)&7) ^ ((a>>6)&4) ^ ((a>>8)&3);
    return a ^ (h<<2);
}

template<int M>
__device__ __forceinline__ void applyw(f2* amp, const float* gw){
    f2 vc  = mk2(gw[0], gw[0]), vs  = mk2(gw[1], gw[1]);
    f2 vcp = mk2(gw[2], gw[2]), vsp = mk2(-gw[3], gw[3]);
    #pragma unroll
    for (int v=0; v<16; ++v) if (!(v & M)){
        f2 a0 = amp[v], a1 = amp[v|M];
        f2 n0 = vc*a0 - vs*a1;
        f2 t  = vs*a0 + vc*a1;
        f2 ts = __builtin_shufflevector(t, t, 1, 0);
        amp[v]   = n0;
        amp[v|M] = vcp*t + vsp*ts;
    }
}
__device__ __forceinline__ void chain3(f2* amp){
    cswap(amp[8],amp[12]); cswap(amp[9],amp[13]); cswap(amp[10],amp[14]); cswap(amp[11],amp[15]);
    cswap(amp[4],amp[6]);  cswap(amp[5],amp[7]);  cswap(amp[12],amp[14]); cswap(amp[13],amp[15]);
    cswap(amp[2],amp[3]);  cswap(amp[6],amp[7]);  cswap(amp[10],amp[11]); cswap(amp[14],amp[15]);
}
__device__ __forceinline__ void swap8u(f2* amp){
    #pragma unroll
    for (int v=0; v<8; ++v) cswap(amp[v], amp[v+8]);
}

template<bool INIT, bool MEASURE>
__global__ __launch_bounds__(1024) void k_vqc(
        const float* __restrict__ wgt,      // [6][16][2]
        const float* __restrict__ fp,       // [64][14][512] (INIT)
        const float* __restrict__ Wr, const float* __restrict__ br,
        const unsigned* __restrict__ sin_,  // fp8x4 per dword (2 amps)
        unsigned* __restrict__ sout,
        float* __restrict__ qacc, float* __restrict__ qnorm,
        unsigned* __restrict__ fincnt,
        float* __restrict__ out, int L, int nrep){
    extern __shared__ unsigned pk[];               // [16384] (INIT/mid only)
    __shared__ float gatesS[64];
    __shared__ float angS[16];
    __shared__ float red16[16];
    f2* Atab = (f2*)(pk + 16384);                  // [256] (INIT only)
    f2* Btab = Atab + 256;                         // [256]
    const int T = threadIdx.x;
    const int c = blockIdx.x >> 6;
    const int b = blockIdx.x & 63;

    for (int rep = 0; rep < nrep; ++rep){
    if (INIT){
        int w = T >> 6, l = T & 63;
        float acc = 0.f;
        #pragma unroll
        for (int k=0;k<8;++k){
            int idx = l + 64*k;
            float s = 0.f;
            #pragma unroll
            for (int seg=0; seg<14; ++seg) s += fp[((b*14 + seg)<<9) + idx];
            acc += (s * (1.0f/3136.0f)) * Wr[w*512 + idx];
        }
        #pragma unroll
        for (int m=32;m>=1;m>>=1) acc += __shfl_xor(acc, m);
        if (l == 0) angS[w] = tanhf(acc + br[w]) * 3.14159265358979323846f;
        __syncthreads();
        if (T < 256){
            int h = T, g = h ^ (h>>1);
            f2 p = mk2(256.f, 0.f);      // x256 state scale
            #pragma unroll
            for (int w2=0; w2<8; ++w2){
                float th = wgt[w2*2+0], ph = wgt[w2*2+1];
                float a  = angS[w2];
                float sb, cb; sincosf(0.5f*(a+th), &sb, &cb);
                float sp, cp; sincosf(ph, &sp, &cp);
                if ((g >> (7-w2)) & 1) p = cmulf(p, mk2(sb*cp, sb*sp));
                else { p.x *= cb; p.y *= cb; }
            }
            Atab[h] = p;
        } else if (T < 512){
            int l8 = T - 256, gl = (l8 ^ (l8>>1)) & 255;
            f2 p = mk2(1.f, 0.f);
            #pragma unroll
            for (int w2=8; w2<16; ++w2){
                float th = wgt[w2*2+0], ph = wgt[w2*2+1];
                float a  = angS[w2];
                float sb, cb; sincosf(0.5f*(a+th), &sb, &cb);
                float sp, cp; sincosf(ph, &sp, &cp);
                if ((gl >> (15-w2)) & 1) p = cmulf(p, mk2(sb*cp, sb*sp));
                else { p.x *= cb; p.y *= cb; }
            }
            Btab[l8] = p;
        } else if (T < 528){
            int idx = T - 512;
            float th = wgt[(L*16+idx)*2+0], ph = wgt[(L*16+idx)*2+1];
            float s_, c_, sp_, cp_;
            sincosf(0.5f*th, &s_, &c_); sincosf(ph, &sp_, &cp_);
            gatesS[idx*4+0]=c_; gatesS[idx*4+1]=s_; gatesS[idx*4+2]=cp_; gatesS[idx*4+3]=sp_;
        }
    } else {
        if (T < 16){
            float th = wgt[(L*16+T)*2+0], ph = wgt[(L*16+T)*2+1];
            float s_, c_, sp_, cp_;
            sincosf(0.5f*th, &s_, &c_); sincosf(ph, &sp_, &cp_);
            gatesS[T*4+0]=c_; gatesS[T*4+1]=s_; gatesS[T*4+2]=cp_; gatesS[T*4+3]=sp_;
        }
    }
    __syncthreads();

    // G4 row for chunk c: wires 0,1 RY*RZ + CNOT(0,1)
    f2 G4r[4];
    {
        float c0_=gatesS[0], s0_=gatesS[1], cp0=gatesS[2], sp0=gatesS[3];
        float c1_=gatesS[4], s1_=gatesS[5], cp1=gatesS[6], sp1=gatesS[7];
        f2 U0[2][2] = {{mk2(c0_,0.f),mk2(-s0_,0.f)},{mk2(s0_*cp0,s0_*sp0),mk2(c0_*cp0,c0_*sp0)}};
        f2 U1[2][2] = {{mk2(c1_,0.f),mk2(-s1_,0.f)},{mk2(s1_*cp1,s1_*sp1),mk2(c1_*cp1,c1_*sp1)}};
        int c1b = c>>1, c0b = c&1;
        #pragma unroll
        for (int cp=0; cp<4; ++cp)
            G4r[cp] = cmulf(U0[c1b][cp>>1], U1[c0b ^ c1b][cp & 1]);
    }

    if (MEASURE){
        #pragma unroll
        for (int cp=0; cp<4; ++cp){ G4r[cp].x *= (1.f/256.f); G4r[cp].y *= (1.f/256.f); }
        const uint2* bb = (const uint2*)(sin_ + ((size_t)b << 15));
        f2 acc2 = mk2(0.f, 0.f);
        #pragma unroll
        for (int v2=0; v2<4; ++v2){
            f2 a[4] = {mk2(0,0),mk2(0,0),mk2(0,0),mk2(0,0)};
            #pragma unroll
            for (int cp=0; cp<4; ++cp){
                uint2 q = bb[(cp<<12)|(v2<<10)|T];
                a[0] = cfma2(G4r[cp], up8<false>(q.x), a[0]);
                a[1] = cfma2(G4r[cp], up8<true >(q.x), a[1]);
                a[2] = cfma2(G4r[cp], up8<false>(q.y), a[2]);
                a[3] = cfma2(G4r[cp], up8<true >(q.y), a[3]);
            }
            #pragma unroll
            for (int u=0;u<4;++u) acc2 += a[u]*a[u];
        }
        float ps = acc2.x + acc2.y;
        #pragma unroll
        for (int m=32;m>=1;m>>=1) ps += __shfl_xor(ps, m);
        if ((T & 63) == 0) red16[T>>6] = ps;
        __syncthreads();
        if (T == 0){
            float tot = 0.f;
            #pragma unroll
            for (int k=0;k<16;++k) tot += red16[k];
            float sgn = (c & 2) ? -1.f : 1.f;
            atomicAdd(&qacc[b], sgn*tot);
            atomicAdd(&qnorm[b], tot);
            unsigned old = __hip_atomic_fetch_add(&fincnt[b], 1u,
                                __ATOMIC_ACQ_REL, __HIP_MEMORY_SCOPE_AGENT);
            if (old == 3u){
                float qa = __hip_atomic_load(&qacc[b], __ATOMIC_ACQUIRE,
                                __HIP_MEMORY_SCOPE_AGENT);
                float qn = __hip_atomic_load(&qnorm[b], __ATOMIC_ACQUIRE,
                                __HIP_MEMORY_SCOPE_AGENT);
                out[b] = 1.f/(1.f + expf(-(qa/qn)));
            }
        }
        return;
    }

    f2 amp[16];   // amp[(v2<<2)|u]: i = (c<<14)|(v2<<12)|(T<<2)|u
    if (INIT){
        f2 Bt[4];
        #pragma unroll
        for (int u=0;u<4;++u) Bt[u] = Btab[((T&63)<<2)|u];
        #pragma unroll
        for (int v2=0; v2<4; ++v2){
            int ihi = (v2<<4) | ((T>>6)&15);
            f2 a[4] = {mk2(0,0),mk2(0,0),mk2(0,0),mk2(0,0)};
            #pragma unroll
            for (int cp=0; cp<4; ++cp){
                f2 Ag = cmulf(G4r[cp], Atab[(cp<<6)|ihi]);
                #pragma unroll
                for (int u=0;u<4;++u) a[u] = cfma2(Ag, Bt[u], a[u]);
            }
            #pragma unroll
            for (int u=0;u<4;++u) amp[(v2<<2)|u] = a[u];
        }
    } else {
        const uint2* bb = (const uint2*)(sin_ + ((size_t)b << 15));
        #pragma unroll
        for (int v2=0; v2<4; ++v2){
            f2 a[4] = {mk2(0,0),mk2(0,0),mk2(0,0),mk2(0,0)};
            #pragma unroll
            for (int cp=0; cp<4; ++cp){
                uint2 q = bb[(cp<<12)|(v2<<10)|T];
                a[0] = cfma2(G4r[cp], up8<false>(q.x), a[0]);
                a[1] = cfma2(G4r[cp], up8<true >(q.x), a[1]);
                a[2] = cfma2(G4r[cp], up8<false>(q.y), a[2]);
                a[3] = cfma2(G4r[cp], up8<true >(q.y), a[3]);
            }
            #pragma unroll
            for (int u=0;u<4;++u) amp[(v2<<2)|u] = a[u];
        }
    }
    // R1: wires 2(b3),3(b2),14(b1),15(b0)
    applyw<8>(amp, gatesS+2*4);
    applyw<4>(amp, gatesS+3*4);
    applyw<2>(amp, gatesS+14*4);
    applyw<1>(amp, gatesS+15*4);
    if (c & 1) swap8u(amp);      // CN(1,2)
    cswap(amp[8],amp[12]); cswap(amp[9],amp[13]); cswap(amp[10],amp[14]); cswap(amp[11],amp[15]); // CN(2,3)
    #pragma unroll
    for (int v2=0; v2<4; ++v2){
        uint4 qq;
        qq.x = pk2(amp[v2*4+0]); qq.y = pk2(amp[v2*4+1]);
        qq.z = pk2(amp[v2*4+2]); qq.w = pk2(amp[v2*4+3]);
        *(uint4*)&pk[SW((v2<<12)|(T<<2))] = qq;
    }
    __syncthreads();
    // R2: wires 4..7 (m11..m8)
    {
        int hi = (T>>8)<<12, lo = T & 255;
        #pragma unroll
        for (int r=0;r<16;++r) amp[r] = up2(pk[SW(hi | (r<<8) | lo)]);
        applyw<8>(amp, gatesS+4*4); applyw<4>(amp, gatesS+5*4);
        applyw<2>(amp, gatesS+6*4); applyw<1>(amp, gatesS+7*4);
        if ((T>>8)&1) swap8u(amp);   // CN(3,4)
        chain3(amp);                 // CN(4,5),(5,6),(6,7)
        #pragma unroll
        for (int r=0;r<16;++r) pk[SW(hi | (r<<8) | lo)] = pk2(amp[r]);
    }
    __syncthreads();
    // R3: wires 8..11 (m7..m4)
    {
        int hi = (T>>4)<<8, lo = T & 15;
        #pragma unroll
        for (int r=0;r<16;++r) amp[r] = up2(pk[SW(hi | (r<<4) | lo)]);
        applyw<8>(amp, gatesS+8*4);  applyw<4>(amp, gatesS+9*4);
        applyw<2>(amp, gatesS+10*4); applyw<1>(amp, gatesS+11*4);
        if ((T>>4)&1) swap8u(amp);   // CN(7,8)
        chain3(amp);                 // CN(8,9),(9,10),(10,11)
        #pragma unroll
        for (int r=0;r<16;++r) pk[SW(hi | (r<<4) | lo)] = pk2(amp[r]);
    }
    __syncthreads();
    // R4: wires 12..15 (m3..m0)
    {
        #pragma unroll
        for (int q=0;q<4;++q){
            uint4 qq = *(const uint4*)&pk[SW((T<<4)|(q<<2))];
            amp[q*4+0]=up2(qq.x); amp[q*4+1]=up2(qq.y);
            amp[q*4+2]=up2(qq.z); amp[q*4+3]=up2(qq.w);
        }
        applyw<8>(amp, gatesS+12*4); applyw<4>(amp, gatesS+13*4);
        if (T & 1) swap8u(amp);      // CN(11,12)
        chain3(amp);                 // CN(12,13),(13,14),(14,15)
        uint4* po = (uint4*)sout + (((size_t)b<<13)|(c<<11)|(T<<1));
        uint4 qa, qb;
        qa.x = pk8(amp[0],amp[1]);  qa.y = pk8(amp[2],amp[3]);
        qa.z = pk8(amp[4],amp[5]);  qa.w = pk8(amp[6],amp[7]);
        qb.x = pk8(amp[8],amp[9]);  qb.y = pk8(amp[10],amp[11]);
        qb.z = pk8(amp[12],amp[13]); qb.w = pk8(amp[14],amp[15]);
        po[0] = qa; po[1] = qb;
    }
    __syncthreads();   // rep separation: R4 reads done before next rep's R1 stores
    }
}

extern "C" void kernel_launch(void* const* d_in, const int* in_sizes, int n_in,
                              void* d_out, int out_size, void* d_ws, size_t ws_size,
                              hipStream_t stream){
    (void)in_sizes; (void)n_in; (void)out_size; (void)ws_size;
    const float* x  = (const float*)d_in[0];
    const float* Wc = (const float*)d_in[1];
    const float* bc = (const float*)d_in[2];
    const float* Wr = (const float*)d_in[3];
    const float* br = (const float*)d_in[4];
    const float* wq = (const float*)d_in[5];
    float* ws     = (float*)d_ws;
    float* fp     = ws;                          // [64][14][512]
    float* qacc   = ws + 458752;
    float* qnorm  = ws + 458816;
    unsigned* fincnt = (unsigned*)(ws + 458880);
    unsigned* SA = (unsigned*)((char*)d_ws + ((size_t)4<<20));
    unsigned* SB = SA + ((size_t)64<<15);        // 8.39MB per buffer
    float* outF = (float*)d_out;

    const int dynC = 224*72*2;           // 32256 B
    const int dynI = 65536 + 4096;       // pk + Atab/Btab
    const int dynM = 65536;              // pk
    (void)hipFuncSetAttribute(reinterpret_cast<const void*>(&k_conv_mfma),
                        hipFuncAttributeMaxDynamicSharedMemorySize, dynC);
    (void)hipFuncSetAttribute(reinterpret_cast<const void*>(&k_vqc<true,false>),
                        hipFuncAttributeMaxDynamicSharedMemorySize, dynI);
    (void)hipFuncSetAttribute(reinterpret_cast<const void*>(&k_vqc<false,false>),
                        hipFuncAttributeMaxDynamicSharedMemorySize, dynM);

    k_conv_mfma<<<64*14,512,dynC,stream>>>(x, Wc, bc, fp, qacc, qnorm, fincnt, 4);  // DIAG x4
    k_vqc<true ,false><<<256,1024,dynI,stream>>>(wq, fp, Wr, br, nullptr, SA, qacc, qnorm, fincnt, outF, 1, 4);  // DIAG x4
    k_vqc<false,false><<<256,1024,dynM,stream>>>(wq, fp, Wr, br, SA, SB, qacc, qnorm, fincnt, outF, 2, 1);
    k_vqc<false,false><<<256,1024,dynM,stream>>>(wq, fp, Wr, br, SB, SA, qacc, qnorm, fincnt, outF, 3, 1);
    k_vqc<false,false><<<256,1024,dynM,stream>>>(wq, fp, Wr, br, SA, SB, qacc, qnorm, fincnt, outF, 4, 1);
    k_vqc<false,true ><<<256,1024,0,   stream>>>(wq, fp, Wr, br, SB, nullptr, qacc, qnorm, fincnt, outF, 5, 1);
}

// Round 17
// 111.088 us; speedup vs baseline: 2.6658x; 2.6658x over previous
//
#include <hip/hip_runtime.h>
#include <hip/hip_bf16.h>
#include <math.h>

// ws layout (floats): [0,917504) fp[64][28][512] conv partials;
//   [917504,917568) qacc; [917568,917632) qnorm; [917632,917696) fincnt(u32)
// fp8 e4m3 state (x256-scaled) ping-pong at byte offset 4MB: SA, SB (each 8.39MB)

typedef _Float16 h4 __attribute__((ext_vector_type(4)));
typedef _Float16 h8 __attribute__((ext_vector_type(8)));
typedef float f32x4 __attribute__((ext_vector_type(4)));
typedef float f2 __attribute__((ext_vector_type(2)));

__device__ __forceinline__ f2 mk2(float a, float b){ f2 r; r.x=a; r.y=b; return r; }
__device__ __forceinline__ f2 cmulf(f2 a, f2 b){
    return mk2(a.x*b.x - a.y*b.y, a.x*b.y + a.y*b.x);
}
__device__ __forceinline__ f2 cfma2(f2 g, f2 q, f2 acc){
    f2 qs = __builtin_shufflevector(q, q, 1, 0);
    acc += mk2(g.x, g.x) * q;
    acc += mk2(-g.y, g.y) * qs;
    return acc;
}
__device__ __forceinline__ void cswap(f2& a, f2& b){ f2 t=a; a=b; b=t; }
__device__ __forceinline__ unsigned pk2(f2 a){
    union{ _Float16 h[2]; unsigned u; } z;
    z.h[0] = (_Float16)a.x; z.h[1] = (_Float16)a.y; return z.u;
}
__device__ __forceinline__ f2 up2(unsigned u){
    union{ unsigned u; _Float16 h[2]; } z; z.u = u;
    return mk2((float)z.h[0], (float)z.h[1]);
}
__device__ __forceinline__ h8 cvt8(float4 a, float4 b){
    h8 r; r[0]=(_Float16)a.x; r[1]=(_Float16)a.y; r[2]=(_Float16)a.z; r[3]=(_Float16)a.w;
    r[4]=(_Float16)b.x; r[5]=(_Float16)b.y; r[6]=(_Float16)b.z; r[7]=(_Float16)b.w; return r;
}

// ---- fp8 e4m3 pack/unpack (OCP; gfx950 HW converts, manual fallback) ----
__device__ __forceinline__ unsigned enc1(float x){
    union{ _Float16 h; unsigned short u; } z; z.h = (_Float16)x;
    unsigned short h = z.u;
    unsigned s = (h>>8) & 0x80u;
    int mag = h & 0x7fff;
    if (mag < 0x2400) return s;
    mag -= 0x2000;
    int r = mag + 0x3F + ((mag>>7)&1);
    int v = r >> 7;
    if (v > 0x7E) v = 0x7E;
    return s | (unsigned)v;
}
__device__ __forceinline__ float dec1(unsigned b){
    unsigned mag = b & 0x7fu;
    if ((mag>>3) == 0) return 0.f;
    unsigned short h = (unsigned short)(((b&0x80u)<<8) | ((mag<<7) + 0x2000));
    union{ unsigned short u; _Float16 h2; } z; z.u = h; return (float)z.h2;
}
__device__ __forceinline__ unsigned pk8(f2 a, f2 b){
#if __has_builtin(__builtin_amdgcn_cvt_pk_fp8_f32)
    unsigned w = (unsigned)__builtin_amdgcn_cvt_pk_fp8_f32(a.x, a.y, 0, false);
    w = (unsigned)__builtin_amdgcn_cvt_pk_fp8_f32(b.x, b.y, (int)w, true);
    return w;
#else
    return enc1(a.x) | (enc1(a.y)<<8) | (enc1(b.x)<<16) | (enc1(b.y)<<24);
#endif
}
template<bool HI>
__device__ __forceinline__ f2 up8(unsigned u){
#if __has_builtin(__builtin_amdgcn_cvt_pk_f32_fp8)
    auto r = __builtin_amdgcn_cvt_pk_f32_fp8((int)u, HI);
    return mk2(r[0], r[1]);
#else
    unsigned b0 = HI ? ((u>>16)&0xffu) : (u&0xffu);
    unsigned b1 = HI ? (u>>24) : ((u>>8)&0xffu);
    return mk2(dec1(b0), dec1(b1));
#endif
}

// ---------------- conv + relu + partial global-avg-pool via MFMA ----------------
// Grid 64*28, 512 thr, 112 positions (2 output rows). LDS 16KB -> ~8 blocks/CU.
__global__ __launch_bounds__(512) void k_conv_mfma(const float* __restrict__ x,
            const float* __restrict__ Wc, const float* __restrict__ bc,
            float* __restrict__ fp, float* __restrict__ qacc,
            float* __restrict__ qnorm, unsigned* __restrict__ fincnt){
    extern __shared__ _Float16 Al[];   // [112][72]
    const int tid = threadIdx.x;
    const int b = blockIdx.x / 28, seg = blockIdx.x % 28;
    for (int idx = tid; idx < 1344; idx += 512){
        int cr = idx / 112, p = idx - cr*112;
        int cc = cr >> 2, r = cr & 3;
        int ro = p / 56, ow = p - ro*56;
        int ih = (seg*2 + ro)*4 + r;
        float4 v = *(const float4*)&x[(((size_t)b*3 + cc)*224 + ih)*224 + ow*4];
        h4 hv; hv[0]=(_Float16)v.x; hv[1]=(_Float16)v.y; hv[2]=(_Float16)v.z; hv[3]=(_Float16)v.w;
        *(h4*)&Al[p*72 + cr*4] = hv;
    }
    for (int idx = tid; idx < 448; idx += 512){
        int p = idx >> 2, j = idx & 3;
        *(h4*)&Al[p*72 + 48 + j*4] = (h4){0,0,0,0};
    }
    if (seg == 0 && tid == 0) qacc[b] = 0.f;
    if (seg == 0 && tid == 1) qnorm[b] = 0.f;
    if (seg == 0 && tid == 2) fincnt[b] = 0u;
    const int wv = tid >> 6, lane = tid & 63;
    const int col = lane & 15, kg = lane >> 4;
    const int n0 = wv * 64;
    const h8 hz = {0,0,0,0,0,0,0,0};
    h8 Bf[4], Bf2[4];
    float bias[4], pool[4];
    #pragma unroll
    for (int nt=0; nt<4; ++nt){
        int ch = n0 + nt*16 + col;
        const float* wr = &Wc[ch*48];
        float4 wa = *(const float4*)&wr[kg*8];
        float4 wb = *(const float4*)&wr[kg*8 + 4];
        Bf[nt] = cvt8(wa, wb);
        if (kg < 2){
            float4 wc4 = *(const float4*)&wr[32 + kg*8];
            float4 wd  = *(const float4*)&wr[36 + kg*8];
            Bf2[nt] = cvt8(wc4, wd);
        } else Bf2[nt] = hz;
        bias[nt] = bc[ch];
        pool[nt] = 0.f;
    }
    __syncthreads();
    #pragma unroll
    for (int mt=0; mt<7; ++mt){
        const _Float16* ar = &Al[(mt*16 + col)*72];
        h8 Af  = *(const h8*)&ar[kg*8];
        h8 Af2 = *(const h8*)&ar[32 + kg*8];
        #pragma unroll
        for (int nt=0; nt<4; ++nt){
            f32x4 acc = {0.f,0.f,0.f,0.f};
            acc = __builtin_amdgcn_mfma_f32_16x16x32_f16(Af,  Bf[nt],  acc, 0,0,0);
            acc = __builtin_amdgcn_mfma_f32_16x16x32_f16(Af2, Bf2[nt], acc, 0,0,0);
            #pragma unroll
            for (int j=0;j<4;++j) pool[nt] += fmaxf(acc[j] + bias[nt], 0.f);
        }
    }
    #pragma unroll
    for (int nt=0; nt<4; ++nt){
        pool[nt] += __shfl_xor(pool[nt], 16);
        pool[nt] += __shfl_xor(pool[nt], 32);
    }
    if (lane < 16){
        float* dst = &fp[((b*28 + seg)<<9) + n0 + lane];
        #pragma unroll
        for (int nt=0; nt<4; ++nt) dst[nt*16] = pool[nt];
    }
}

// ---------------- VQC layer kernels ----------------
__device__ __forceinline__ int SW(int a){
    int h = ((a>>5)&7) ^ ((a>>6)&4) ^ ((a>>8)&3);
    return a ^ (h<<2);
}

template<int M>
__device__ __forceinline__ void applyw(f2* amp, const float* gw){
    f2 vc  = mk2(gw[0], gw[0]), vs  = mk2(gw[1], gw[1]);
    f2 vcp = mk2(gw[2], gw[2]), vsp = mk2(-gw[3], gw[3]);
    #pragma unroll
    for (int v=0; v<16; ++v) if (!(v & M)){
        f2 a0 = amp[v], a1 = amp[v|M];
        f2 n0 = vc*a0 - vs*a1;
        f2 t  = vs*a0 + vc*a1;
        f2 ts = __builtin_shufflevector(t, t, 1, 0);
        amp[v]   = n0;
        amp[v|M] = vcp*t + vsp*ts;
    }
}
__device__ __forceinline__ void chain3(f2* amp){
    cswap(amp[8],amp[12]); cswap(amp[9],amp[13]); cswap(amp[10],amp[14]); cswap(amp[11],amp[15]);
    cswap(amp[4],amp[6]);  cswap(amp[5],amp[7]);  cswap(amp[12],amp[14]); cswap(amp[13],amp[15]);
    cswap(amp[2],amp[3]);  cswap(amp[6],amp[7]);  cswap(amp[10],amp[11]); cswap(amp[14],amp[15]);
}
__device__ __forceinline__ void swap8u(f2* amp){
    #pragma unroll
    for (int v=0; v<8; ++v) cswap(amp[v], amp[v+8]);
}

template<bool INIT, bool MEASURE>
__global__ __launch_bounds__(1024) void k_vqc(
        const float* __restrict__ wgt,      // [6][16][2]
        const float* __restrict__ fp,       // [64][28][512] (INIT)
        const float* __restrict__ Wr, const float* __restrict__ br,
        const unsigned* __restrict__ sin_,  // fp8x4 per dword (2 amps)
        unsigned* __restrict__ sout,
        float* __restrict__ qacc, float* __restrict__ qnorm,
        unsigned* __restrict__ fincnt,
        float* __restrict__ out, int L){
    extern __shared__ unsigned pk[];               // [16384] (INIT/mid only)
    __shared__ float gatesS[64];
    __shared__ float angS[16];
    __shared__ float red16[16];
    __shared__ float featL[512];
    f2* Atab = (f2*)(pk + 16384);                  // [256] (INIT only)
    f2* Btab = Atab + 256;                         // [256]
    const int T = threadIdx.x;
    const int c = blockIdx.x >> 6;     // chunk; blockIdx=c*64+b -> sample XCD-local
    const int b = blockIdx.x & 63;     // sample

    if (INIT){
        // stage feat sums once (coalesced), then 16-wave reduce from LDS
        if (T < 512){
            float s = 0.f;
            #pragma unroll
            for (int seg=0; seg<28; ++seg) s += fp[((b*28 + seg)<<9) + T];
            featL[T] = s;
        }
        __syncthreads();
        int w = T >> 6, l = T & 63;
        float acc = 0.f;
        #pragma unroll
        for (int k=0;k<8;++k){
            int idx = l + 64*k;
            acc += (featL[idx] * (1.0f/3136.0f)) * Wr[w*512 + idx];
        }
        #pragma unroll
        for (int m=32;m>=1;m>>=1) acc += __shfl_xor(acc, m);
        if (l == 0) angS[w] = tanhf(acc + br[w]) * 3.14159265358979323846f;
        __syncthreads();
        if (T < 256){
            int h = T, g = h ^ (h>>1);
            f2 p = mk2(256.f, 0.f);      // x256 state scale folded here
            #pragma unroll
            for (int w2=0; w2<8; ++w2){
                float th = wgt[w2*2+0], ph = wgt[w2*2+1];
                float a  = angS[w2];
                float sb, cb; sincosf(0.5f*(a+th), &sb, &cb);
                float sp, cp; sincosf(ph, &sp, &cp);
                if ((g >> (7-w2)) & 1) p = cmulf(p, mk2(sb*cp, sb*sp));
                else { p.x *= cb; p.y *= cb; }
            }
            Atab[h] = p;
        } else if (T < 512){
            int l8 = T - 256, gl = (l8 ^ (l8>>1)) & 255;
            f2 p = mk2(1.f, 0.f);
            #pragma unroll
            for (int w2=8; w2<16; ++w2){
                float th = wgt[w2*2+0], ph = wgt[w2*2+1];
                float a  = angS[w2];
                float sb, cb; sincosf(0.5f*(a+th), &sb, &cb);
                float sp, cp; sincosf(ph, &sp, &cp);
                if ((gl >> (15-w2)) & 1) p = cmulf(p, mk2(sb*cp, sb*sp));
                else { p.x *= cb; p.y *= cb; }
            }
            Btab[l8] = p;
        } else if (T < 528){
            int idx = T - 512;
            float th = wgt[(L*16+idx)*2+0], ph = wgt[(L*16+idx)*2+1];
            float s_, c_, sp_, cp_;
            sincosf(0.5f*th, &s_, &c_); sincosf(ph, &sp_, &cp_);
            gatesS[idx*4+0]=c_; gatesS[idx*4+1]=s_; gatesS[idx*4+2]=cp_; gatesS[idx*4+3]=sp_;
        }
    } else {
        if (T < 16){
            float th = wgt[(L*16+T)*2+0], ph = wgt[(L*16+T)*2+1];
            float s_, c_, sp_, cp_;
            sincosf(0.5f*th, &s_, &c_); sincosf(ph, &sp_, &cp_);
            gatesS[T*4+0]=c_; gatesS[T*4+1]=s_; gatesS[T*4+2]=cp_; gatesS[T*4+3]=sp_;
        }
    }
    __syncthreads();

    // G4 row for chunk c: wires 0,1 RY*RZ + CNOT(0,1)
    f2 G4r[4];
    {
        float c0_=gatesS[0], s0_=gatesS[1], cp0=gatesS[2], sp0=gatesS[3];
        float c1_=gatesS[4], s1_=gatesS[5], cp1=gatesS[6], sp1=gatesS[7];
        f2 U0[2][2] = {{mk2(c0_,0.f),mk2(-s0_,0.f)},{mk2(s0_*cp0,s0_*sp0),mk2(c0_*cp0,c0_*sp0)}};
        f2 U1[2][2] = {{mk2(c1_,0.f),mk2(-s1_,0.f)},{mk2(s1_*cp1,s1_*sp1),mk2(c1_*cp1,c1_*sp1)}};
        int c1b = c>>1, c0b = c&1;
        #pragma unroll
        for (int cp=0; cp<4; ++cp)
            G4r[cp] = cmulf(U0[c1b][cp>>1], U1[c0b ^ c1b][cp & 1]);
    }

    if (MEASURE){
        #pragma unroll
        for (int cp=0; cp<4; ++cp){ G4r[cp].x *= (1.f/256.f); G4r[cp].y *= (1.f/256.f); }
        const uint2* bb = (const uint2*)(sin_ + ((size_t)b << 15));
        f2 acc2 = mk2(0.f, 0.f);
        #pragma unroll
        for (int v2=0; v2<4; ++v2){
            f2 a[4] = {mk2(0,0),mk2(0,0),mk2(0,0),mk2(0,0)};
            #pragma unroll
            for (int cp=0; cp<4; ++cp){
                uint2 q = bb[(cp<<12)|(v2<<10)|T];
                a[0] = cfma2(G4r[cp], up8<false>(q.x), a[0]);
                a[1] = cfma2(G4r[cp], up8<true >(q.x), a[1]);
                a[2] = cfma2(G4r[cp], up8<false>(q.y), a[2]);
                a[3] = cfma2(G4r[cp], up8<true >(q.y), a[3]);
            }
            #pragma unroll
            for (int u=0;u<4;++u) acc2 += a[u]*a[u];
        }
        float ps = acc2.x + acc2.y;
        #pragma unroll
        for (int m=32;m>=1;m>>=1) ps += __shfl_xor(ps, m);
        if ((T & 63) == 0) red16[T>>6] = ps;
        __syncthreads();
        if (T == 0){
            float tot = 0.f;
            #pragma unroll
            for (int k=0;k<16;++k) tot += red16[k];
            float sgn = (c & 2) ? -1.f : 1.f;   // wire0 = c bit1
            atomicAdd(&qacc[b], sgn*tot);
            atomicAdd(&qnorm[b], tot);
            unsigned old = __hip_atomic_fetch_add(&fincnt[b], 1u,
                                __ATOMIC_ACQ_REL, __HIP_MEMORY_SCOPE_AGENT);
            if (old == 3u){
                float qa = __hip_atomic_load(&qacc[b], __ATOMIC_ACQUIRE,
                                __HIP_MEMORY_SCOPE_AGENT);
                float qn = __hip_atomic_load(&qnorm[b], __ATOMIC_ACQUIRE,
                                __HIP_MEMORY_SCOPE_AGENT);
                out[b] = 1.f/(1.f + expf(-(qa/qn)));
            }
        }
        return;
    }

    f2 amp[16];   // amp[(v2<<2)|u]: i = (c<<14)|(v2<<12)|(T<<2)|u
    if (INIT){
        f2 Bt[4];
        #pragma unroll
        for (int u=0;u<4;++u) Bt[u] = Btab[((T&63)<<2)|u];
        #pragma unroll
        for (int v2=0; v2<4; ++v2){
            int ihi = (v2<<4) | ((T>>6)&15);
            f2 a[4] = {mk2(0,0),mk2(0,0),mk2(0,0),mk2(0,0)};
            #pragma unroll
            for (int cp=0; cp<4; ++cp){
                f2 Ag = cmulf(G4r[cp], Atab[(cp<<6)|ihi]);
                #pragma unroll
                for (int u=0;u<4;++u) a[u] = cfma2(Ag, Bt[u], a[u]);
            }
            #pragma unroll
            for (int u=0;u<4;++u) amp[(v2<<2)|u] = a[u];
        }
    } else {
        const uint2* bb = (const uint2*)(sin_ + ((size_t)b << 15));
        #pragma unroll
        for (int v2=0; v2<4; ++v2){
            f2 a[4] = {mk2(0,0),mk2(0,0),mk2(0,0),mk2(0,0)};
            #pragma unroll
            for (int cp=0; cp<4; ++cp){
                uint2 q = bb[(cp<<12)|(v2<<10)|T];
                a[0] = cfma2(G4r[cp], up8<false>(q.x), a[0]);
                a[1] = cfma2(G4r[cp], up8<true >(q.x), a[1]);
                a[2] = cfma2(G4r[cp], up8<false>(q.y), a[2]);
                a[3] = cfma2(G4r[cp], up8<true >(q.y), a[3]);
            }
            #pragma unroll
            for (int u=0;u<4;++u) amp[(v2<<2)|u] = a[u];
        }
    }
    // R1: wires 2(b3),3(b2),14(b1),15(b0)
    applyw<8>(amp, gatesS+2*4);
    applyw<4>(amp, gatesS+3*4);
    applyw<2>(amp, gatesS+14*4);
    applyw<1>(amp, gatesS+15*4);
    if (c & 1) swap8u(amp);      // CN(1,2)
    cswap(amp[8],amp[12]); cswap(amp[9],amp[13]); cswap(amp[10],amp[14]); cswap(amp[11],amp[15]); // CN(2,3)
    #pragma unroll
    for (int v2=0; v2<4; ++v2){
        uint4 qq;
        qq.x = pk2(amp[v2*4+0]); qq.y = pk2(amp[v2*4+1]);
        qq.z = pk2(amp[v2*4+2]); qq.w = pk2(amp[v2*4+3]);
        *(uint4*)&pk[SW((v2<<12)|(T<<2))] = qq;
    }
    __syncthreads();
    // R2: wires 4..7 (m11..m8)
    {
        int hi = (T>>8)<<12, lo = T & 255;
        #pragma unroll
        for (int r=0;r<16;++r) amp[r] = up2(pk[SW(hi | (r<<8) | lo)]);
        applyw<8>(amp, gatesS+4*4); applyw<4>(amp, gatesS+5*4);
        applyw<2>(amp, gatesS+6*4); applyw<1>(amp, gatesS+7*4);
        if ((T>>8)&1) swap8u(amp);   // CN(3,4)
        chain3(amp);                 // CN(4,5),(5,6),(6,7)
        #pragma unroll
        for (int r=0;r<16;++r) pk[SW(hi | (r<<8) | lo)] = pk2(amp[r]);
    }
    __syncthreads();
    // R3: wires 8..11 (m7..m4)
    {
        int hi = (T>>4)<<8, lo = T & 15;
        #pragma unroll
        for (int r=0;r<16;++r) amp[r] = up2(pk[SW(hi | (r<<4) | lo)]);
        applyw<8>(amp, gatesS+8*4);  applyw<4>(amp, gatesS+9*4);
        applyw<2>(amp, gatesS+10*4); applyw<1>(amp, gatesS+11*4);
        if ((T>>4)&1) swap8u(amp);   // CN(7,8)
        chain3(amp);                 // CN(8,9),(9,10),(10,11)
        #pragma unroll
        for (int r=0;r<16;++r) pk[SW(hi | (r<<4) | lo)] = pk2(amp[r]);
    }
    __syncthreads();
    // R4: wires 12..15 (m3..m0)
    {
        #pragma unroll
        for (int q=0;q<4;++q){
            uint4 qq = *(const uint4*)&pk[SW((T<<4)|(q<<2))];
            amp[q*4+0]=up2(qq.x); amp[q*4+1]=up2(qq.y);
            amp[q*4+2]=up2(qq.z); amp[q*4+3]=up2(qq.w);
        }
        applyw<8>(amp, gatesS+12*4); applyw<4>(amp, gatesS+13*4);
        if (T & 1) swap8u(amp);      // CN(11,12)
        chain3(amp);                 // CN(12,13),(13,14),(14,15)
        uint4* po = (uint4*)sout + (((size_t)b<<13)|(c<<11)|(T<<1));
        uint4 qa, qb;
        qa.x = pk8(amp[0],amp[1]);  qa.y = pk8(amp[2],amp[3]);
        qa.z = pk8(amp[4],amp[5]);  qa.w = pk8(amp[6],amp[7]);
        qb.x = pk8(amp[8],amp[9]);  qb.y = pk8(amp[10],amp[11]);
        qb.z = pk8(amp[12],amp[13]); qb.w = pk8(amp[14],amp[15]);
        po[0] = qa; po[1] = qb;
    }
}

extern "C" void kernel_launch(void* const* d_in, const int* in_sizes, int n_in,
                              void* d_out, int out_size, void* d_ws, size_t ws_size,
                              hipStream_t stream){
    (void)in_sizes; (void)n_in; (void)out_size; (void)ws_size;
    const float* x  = (const float*)d_in[0];
    const float* Wc = (const float*)d_in[1];
    const float* bc = (const float*)d_in[2];
    const float* Wr = (const float*)d_in[3];
    const float* br = (const float*)d_in[4];
    const float* wq = (const float*)d_in[5];
    float* ws     = (float*)d_ws;
    float* fp     = ws;                          // [64][28][512]
    float* qacc   = ws + 917504;
    float* qnorm  = ws + 917568;
    unsigned* fincnt = (unsigned*)(ws + 917632);
    unsigned* SA = (unsigned*)((char*)d_ws + ((size_t)4<<20));
    unsigned* SB = SA + ((size_t)64<<15);        // 8.39MB per buffer
    float* outF = (float*)d_out;

    const int dynC = 112*72*2;           // 16128 B -> ~8 blocks/CU
    const int dynI = 65536 + 4096;       // pk + Atab/Btab
    const int dynM = 65536;              // pk
    (void)hipFuncSetAttribute(reinterpret_cast<const void*>(&k_conv_mfma),
                        hipFuncAttributeMaxDynamicSharedMemorySize, dynC);
    (void)hipFuncSetAttribute(reinterpret_cast<const void*>(&k_vqc<true,false>),
                        hipFuncAttributeMaxDynamicSharedMemorySize, dynI);
    (void)hipFuncSetAttribute(reinterpret_cast<const void*>(&k_vqc<false,false>),
                        hipFuncAttributeMaxDynamicSharedMemorySize, dynM);

    k_conv_mfma<<<64*28,512,dynC,stream>>>(x, Wc, bc, fp, qacc, qnorm, fincnt);
    k_vqc<true ,false><<<256,1024,dynI,stream>>>(wq, fp, Wr, br, nullptr, SA, qacc, qnorm, fincnt, outF, 1);
    k_vqc<false,false><<<256,1024,dynM,stream>>>(wq, fp, Wr, br, SA, SB, qacc, qnorm, fincnt, outF, 2);
    k_vqc<false,false><<<256,1024,dynM,stream>>>(wq, fp, Wr, br, SB, SA, qacc, qnorm, fincnt, outF, 3);
    k_vqc<false,false><<<256,1024,dynM,stream>>>(wq, fp, Wr, br, SA, SB, qacc, qnorm, fincnt, outF, 4);
    k_vqc<false,true ><<<256,1024,0,   stream>>>(wq, fp, Wr, br, SB, nullptr, qacc, qnorm, fincnt, outF, 5);
}

// Round 18
// 51.879 us; speedup vs baseline: 5.7083x; 2.1413x over previous
//
#include <hip/hip_runtime.h>
#include <hip/hip_bf16.h>
#include <math.h>

// ws layout (floats): [0,917504) fp[64][28][512] conv partials. Nothing else needed.

typedef _Float16 h4 __attribute__((ext_vector_type(4)));
typedef _Float16 h8 __attribute__((ext_vector_type(8)));
typedef float f32x4 __attribute__((ext_vector_type(4)));

__device__ __forceinline__ h8 cvt8(float4 a, float4 b){
    h8 r; r[0]=(_Float16)a.x; r[1]=(_Float16)a.y; r[2]=(_Float16)a.z; r[3]=(_Float16)a.w;
    r[4]=(_Float16)b.x; r[5]=(_Float16)b.y; r[6]=(_Float16)b.z; r[7]=(_Float16)b.w; return r;
}

// ---------------- conv + relu + partial global-avg-pool via MFMA ----------------
// Grid 64*28, 512 thr, 112 positions (2 output rows). LDS 16KB -> ~8 blocks/CU.
__global__ __launch_bounds__(512) void k_conv_mfma(const float* __restrict__ x,
            const float* __restrict__ Wc, const float* __restrict__ bc,
            float* __restrict__ fp){
    extern __shared__ _Float16 Al[];   // [112][72]
    const int tid = threadIdx.x;
    const int b = blockIdx.x / 28, seg = blockIdx.x % 28;
    for (int idx = tid; idx < 1344; idx += 512){
        int cr = idx / 112, p = idx - cr*112;
        int cc = cr >> 2, r = cr & 3;
        int ro = p / 56, ow = p - ro*56;
        int ih = (seg*2 + ro)*4 + r;
        float4 v = *(const float4*)&x[(((size_t)b*3 + cc)*224 + ih)*224 + ow*4];
        h4 hv; hv[0]=(_Float16)v.x; hv[1]=(_Float16)v.y; hv[2]=(_Float16)v.z; hv[3]=(_Float16)v.w;
        *(h4*)&Al[p*72 + cr*4] = hv;
    }
    for (int idx = tid; idx < 448; idx += 512){
        int p = idx >> 2, j = idx & 3;
        *(h4*)&Al[p*72 + 48 + j*4] = (h4){0,0,0,0};
    }
    const int wv = tid >> 6, lane = tid & 63;
    const int col = lane & 15, kg = lane >> 4;
    const int n0 = wv * 64;
    const h8 hz = {0,0,0,0,0,0,0,0};
    h8 Bf[4], Bf2[4];
    float bias[4], pool[4];
    #pragma unroll
    for (int nt=0; nt<4; ++nt){
        int ch = n0 + nt*16 + col;
        const float* wr = &Wc[ch*48];
        float4 wa = *(const float4*)&wr[kg*8];
        float4 wb = *(const float4*)&wr[kg*8 + 4];
        Bf[nt] = cvt8(wa, wb);
        if (kg < 2){
            float4 wc4 = *(const float4*)&wr[32 + kg*8];
            float4 wd  = *(const float4*)&wr[36 + kg*8];
            Bf2[nt] = cvt8(wc4, wd);
        } else Bf2[nt] = hz;
        bias[nt] = bc[ch];
        pool[nt] = 0.f;
    }
    __syncthreads();
    #pragma unroll
    for (int mt=0; mt<7; ++mt){
        const _Float16* ar = &Al[(mt*16 + col)*72];
        h8 Af  = *(const h8*)&ar[kg*8];
        h8 Af2 = *(const h8*)&ar[32 + kg*8];
        #pragma unroll
        for (int nt=0; nt<4; ++nt){
            f32x4 acc = {0.f,0.f,0.f,0.f};
            acc = __builtin_amdgcn_mfma_f32_16x16x32_f16(Af,  Bf[nt],  acc, 0,0,0);
            acc = __builtin_amdgcn_mfma_f32_16x16x32_f16(Af2, Bf2[nt], acc, 0,0,0);
            #pragma unroll
            for (int j=0;j<4;++j) pool[nt] += fmaxf(acc[j] + bias[nt], 0.f);
        }
    }
    #pragma unroll
    for (int nt=0; nt<4; ++nt){
        pool[nt] += __shfl_xor(pool[nt], 16);
        pool[nt] += __shfl_xor(pool[nt], 32);
    }
    if (lane < 16){
        float* dst = &fp[((b*28 + seg)<<9) + n0 + lane];
        #pragma unroll
        for (int nt=0; nt<4; ++nt) dst[nt*16] = pool[nt];
    }
}

// ---------------- light-cone VQC: 6-qubit statevector, one wave per sample ----------------
// M = U^dag Z0 U is supported on wires 0..5 (ascending CNOT chain => backward light
// cone grows 1 wire/layer). out = <phi|V^dag Z0 V|phi>, V = restricted 6-qubit circuit.
// Lane j holds amp[j] (6-bit index, wire w <-> bit 5-w). All gates via shfl_xor.
__global__ __launch_bounds__(64) void k_vqc6(
        const float* __restrict__ wgt,   // [6][16][2]
        const float* __restrict__ fp,    // [64][28][512]
        const float* __restrict__ Wr, const float* __restrict__ br,
        float* __restrict__ out){
    __shared__ float gates[36][4];   // [layer*6+wire]{c,s,cp,sp}
    __shared__ float enc[6][2];      // encoding (c,s) per wire 0..5
    __shared__ float angS[6];
    const int l = threadIdx.x;
    const int b = blockIdx.x;

    // feat sums: lane l covers channels l+64k
    float fs[8];
    #pragma unroll
    for (int k=0;k<8;++k){
        int ch = l + 64*k;
        float s = 0.f;
        #pragma unroll 4
        for (int seg=0; seg<28; ++seg) s += fp[((b*28 + seg)<<9) + ch];
        fs[k] = s;
    }
    // angles for wires 0..5 only (light cone)
    for (int w=0; w<6; ++w){
        float acc = 0.f;
        #pragma unroll
        for (int k=0;k<8;++k)
            acc += (fs[k] * (1.0f/3136.0f)) * Wr[w*512 + l + 64*k];
        #pragma unroll
        for (int m=32;m>=1;m>>=1) acc += __shfl_xor(acc, m);
        if (l == 0) angS[w] = tanhf(acc + br[w]) * 3.14159265358979323846f;
    }
    __syncthreads();
    if (l < 36){
        int L = l/6, w = l%6;
        float th = wgt[(L*16+w)*2+0], ph = wgt[(L*16+w)*2+1];
        float s_, c_, sp_, cp_;
        sincosf(0.5f*th, &s_, &c_); sincosf(ph, &sp_, &cp_);
        gates[l][0]=c_; gates[l][1]=s_; gates[l][2]=cp_; gates[l][3]=sp_;
    } else if (l < 42){
        int w = l - 36;
        float sb, cb; sincosf(0.5f*angS[w], &sb, &cb);
        enc[w][0] = cb; enc[w][1] = sb;
    }
    __syncthreads();

    // product state phi
    float re, im = 0.f;
    {
        float p = 1.f;
        #pragma unroll
        for (int w=0; w<6; ++w) p *= ((l >> (5-w)) & 1) ? enc[w][1] : enc[w][0];
        re = p;
    }
    // 6 layers: RY+RZ on wires 0..5, chain CN(0,1)..CN(4,5)
    for (int L=0; L<6; ++L){
        #pragma unroll
        for (int w=0; w<6; ++w){
            const int msk = 1 << (5-w);
            const float c_ = gates[L*6+w][0], s_ = gates[L*6+w][1];
            const float cp_ = gates[L*6+w][2], sp_ = gates[L*6+w][3];
            float pr = __shfl_xor(re, msk), pi = __shfl_xor(im, msk);
            float nr, ni;
            if (l & msk){
                nr = s_*pr + c_*re;  ni = s_*pi + c_*im;
                float tr = nr*cp_ - ni*sp_;            // RZ phase on |1>
                ni = nr*sp_ + ni*cp_;  nr = tr;
            } else {
                nr = c_*re - s_*pr;  ni = c_*im - s_*pi;
            }
            re = nr; im = ni;
        }
        #pragma unroll
        for (int k=0; k<5; ++k){
            const int cb = 5-k, tm = 1 << (4-k);
            float pr = __shfl_xor(re, tm), pi = __shfl_xor(im, tm);
            bool ct = (l >> cb) & 1;
            re = ct ? pr : re;  im = ct ? pi : im;
        }
    }
    // <Z0>: wire 0 = bit 5
    float p = (((l >> 5) & 1) ? -1.f : 1.f) * (re*re + im*im);
    #pragma unroll
    for (int m=32;m>=1;m>>=1) p += __shfl_xor(p, m);
    if (l == 0) out[b] = 1.f/(1.f + expf(-p));
}

extern "C" void kernel_launch(void* const* d_in, const int* in_sizes, int n_in,
                              void* d_out, int out_size, void* d_ws, size_t ws_size,
                              hipStream_t stream){
    (void)in_sizes; (void)n_in; (void)out_size; (void)ws_size;
    const float* x  = (const float*)d_in[0];
    const float* Wc = (const float*)d_in[1];
    const float* bc = (const float*)d_in[2];
    const float* Wr = (const float*)d_in[3];
    const float* br = (const float*)d_in[4];
    const float* wq = (const float*)d_in[5];
    float* fp   = (float*)d_ws;                  // [64][28][512]
    float* outF = (float*)d_out;

    const int dynC = 112*72*2;           // 16128 B -> ~8 blocks/CU
    (void)hipFuncSetAttribute(reinterpret_cast<const void*>(&k_conv_mfma),
                        hipFuncAttributeMaxDynamicSharedMemorySize, dynC);

    k_conv_mfma<<<64*28,512,dynC,stream>>>(x, Wc, bc, fp);
    k_vqc6<<<64,64,0,stream>>>(wq, fp, Wr, br, outF);
}

// Round 19
// 36.557 us; speedup vs baseline: 8.1009x; 1.4191x over previous
//
#include <hip/hip_runtime.h>
#include <hip/hip_bf16.h>
#include <math.h>

// ws layout (floats): [0,917504) fp[64][28][512] conv partials. Nothing else needed.

typedef _Float16 h4 __attribute__((ext_vector_type(4)));
typedef _Float16 h8 __attribute__((ext_vector_type(8)));
typedef float f32x4 __attribute__((ext_vector_type(4)));

__device__ __forceinline__ h8 cvt8(float4 a, float4 b){
    h8 r; r[0]=(_Float16)a.x; r[1]=(_Float16)a.y; r[2]=(_Float16)a.z; r[3]=(_Float16)a.w;
    r[4]=(_Float16)b.x; r[5]=(_Float16)b.y; r[6]=(_Float16)b.z; r[7]=(_Float16)b.w; return r;
}

// ---------------- conv + relu + partial global-avg-pool via MFMA ----------------
// Grid 64*28, 512 thr, 112 positions (2 output rows). LDS 16KB.
__global__ __launch_bounds__(512) void k_conv_mfma(const float* __restrict__ x,
            const float* __restrict__ Wc, const float* __restrict__ bc,
            float* __restrict__ fp){
    extern __shared__ _Float16 Al[];   // [112][72]
    const int tid = threadIdx.x;
    const int b = blockIdx.x / 28, seg = blockIdx.x % 28;
    for (int idx = tid; idx < 1344; idx += 512){
        int cr = idx / 112, p = idx - cr*112;
        int cc = cr >> 2, r = cr & 3;
        int ro = p / 56, ow = p - ro*56;
        int ih = (seg*2 + ro)*4 + r;
        float4 v = *(const float4*)&x[(((size_t)b*3 + cc)*224 + ih)*224 + ow*4];
        h4 hv; hv[0]=(_Float16)v.x; hv[1]=(_Float16)v.y; hv[2]=(_Float16)v.z; hv[3]=(_Float16)v.w;
        *(h4*)&Al[p*72 + cr*4] = hv;
    }
    for (int idx = tid; idx < 448; idx += 512){
        int p = idx >> 2, j = idx & 3;
        *(h4*)&Al[p*72 + 48 + j*4] = (h4){0,0,0,0};
    }
    const int wv = tid >> 6, lane = tid & 63;
    const int col = lane & 15, kg = lane >> 4;
    const int n0 = wv * 64;
    const h8 hz = {0,0,0,0,0,0,0,0};
    h8 Bf[4], Bf2[4];
    float bias[4], pool[4];
    #pragma unroll
    for (int nt=0; nt<4; ++nt){
        int ch = n0 + nt*16 + col;
        const float* wr = &Wc[ch*48];
        float4 wa = *(const float4*)&wr[kg*8];
        float4 wb = *(const float4*)&wr[kg*8 + 4];
        Bf[nt] = cvt8(wa, wb);
        if (kg < 2){
            float4 wc4 = *(const float4*)&wr[32 + kg*8];
            float4 wd  = *(const float4*)&wr[36 + kg*8];
            Bf2[nt] = cvt8(wc4, wd);
        } else Bf2[nt] = hz;
        bias[nt] = bc[ch];
        pool[nt] = 0.f;
    }
    __syncthreads();
    #pragma unroll
    for (int mt=0; mt<7; ++mt){
        const _Float16* ar = &Al[(mt*16 + col)*72];
        h8 Af  = *(const h8*)&ar[kg*8];
        h8 Af2 = *(const h8*)&ar[32 + kg*8];
        #pragma unroll
        for (int nt=0; nt<4; ++nt){
            f32x4 acc = {0.f,0.f,0.f,0.f};
            acc = __builtin_amdgcn_mfma_f32_16x16x32_f16(Af,  Bf[nt],  acc, 0,0,0);
            acc = __builtin_amdgcn_mfma_f32_16x16x32_f16(Af2, Bf2[nt], acc, 0,0,0);
            #pragma unroll
            for (int j=0;j<4;++j) pool[nt] += fmaxf(acc[j] + bias[nt], 0.f);
        }
    }
    #pragma unroll
    for (int nt=0; nt<4; ++nt){
        pool[nt] += __shfl_xor(pool[nt], 16);
        pool[nt] += __shfl_xor(pool[nt], 32);
    }
    if (lane < 16){
        float* dst = &fp[((b*28 + seg)<<9) + n0 + lane];
        #pragma unroll
        for (int nt=0; nt<4; ++nt) dst[nt*16] = pool[nt];
    }
}

// ---------------- light-cone VQC: 6-qubit statevector ----------------
// M = U^dag Z0 U supported on wires 0..5 (ascending CNOT chain: backward light
// cone grows 1 wire/layer). 512 thr: feat stage (8-wave TLP) -> 6-wave reduce ->
// wave 0 runs the 64-amp circuit via shfl_xor.
__global__ __launch_bounds__(512) void k_vqc6(
        const float* __restrict__ wgt,   // [6][16][2]
        const float* __restrict__ fp,    // [64][28][512]
        const float* __restrict__ Wr, const float* __restrict__ br,
        float* __restrict__ out){
    __shared__ float featL[512];
    __shared__ float gates[36][4];   // [layer*6+wire]{c,s,cp,sp}
    __shared__ float enc[6][2];      // encoding (c,s) per wire 0..5
    __shared__ float angS[6];
    const int T = threadIdx.x;
    const int b = blockIdx.x;

    // feat stage: thread T sums 28 segs for channel T (coalesced, 8 waves)
    {
        float s = 0.f;
        #pragma unroll 4
        for (int seg=0; seg<28; ++seg) s += fp[((b*28 + seg)<<9) + T];
        featL[T] = s;
    }
    __syncthreads();
    // wires 0..5: wave w reduces dot(featL, Wr[w])
    {
        int w = T >> 6, l = T & 63;
        if (w < 6){
            float acc = 0.f;
            #pragma unroll
            for (int k=0;k<8;++k)
                acc += (featL[l + 64*k] * (1.0f/3136.0f)) * Wr[w*512 + l + 64*k];
            #pragma unroll
            for (int m=32;m>=1;m>>=1) acc += __shfl_xor(acc, m);
            if (l == 0) angS[w] = tanhf(acc + br[w]) * 3.14159265358979323846f;
        }
    }
    __syncthreads();
    if (T < 36){
        int L = T/6, w = T%6;
        float th = wgt[(L*16+w)*2+0], ph = wgt[(L*16+w)*2+1];
        float s_, c_, sp_, cp_;
        sincosf(0.5f*th, &s_, &c_); sincosf(ph, &sp_, &cp_);
        gates[T][0]=c_; gates[T][1]=s_; gates[T][2]=cp_; gates[T][3]=sp_;
    } else if (T < 42){
        int w = T - 36;
        float sb, cb; sincosf(0.5f*angS[w], &sb, &cb);
        enc[w][0] = cb; enc[w][1] = sb;
    }
    __syncthreads();
    if (T >= 64) return;            // circuit on wave 0 only
    const int l = T;

    // product state phi
    float re, im = 0.f;
    {
        float p = 1.f;
        #pragma unroll
        for (int w=0; w<6; ++w) p *= ((l >> (5-w)) & 1) ? enc[w][1] : enc[w][0];
        re = p;
    }
    // 6 layers: RY+RZ on wires 0..5, chain CN(0,1)..CN(4,5)
    for (int L=0; L<6; ++L){
        #pragma unroll
        for (int w=0; w<6; ++w){
            const int msk = 1 << (5-w);
            const float c_ = gates[L*6+w][0], s_ = gates[L*6+w][1];
            const float cp_ = gates[L*6+w][2], sp_ = gates[L*6+w][3];
            float pr = __shfl_xor(re, msk), pi = __shfl_xor(im, msk);
            float nr, ni;
            if (l & msk){
                nr = s_*pr + c_*re;  ni = s_*pi + c_*im;
                float tr = nr*cp_ - ni*sp_;            // RZ phase on |1>
                ni = nr*sp_ + ni*cp_;  nr = tr;
            } else {
                nr = c_*re - s_*pr;  ni = c_*im - s_*pi;
            }
            re = nr; im = ni;
        }
        #pragma unroll
        for (int k=0; k<5; ++k){
            const int cb = 5-k, tm = 1 << (4-k);
            float pr = __shfl_xor(re, tm), pi = __shfl_xor(im, tm);
            bool ct = (l >> cb) & 1;
            re = ct ? pr : re;  im = ct ? pi : im;
        }
    }
    // <Z0>: wire 0 = bit 5
    float p = (((l >> 5) & 1) ? -1.f : 1.f) * (re*re + im*im);
    #pragma unroll
    for (int m=32;m>=1;m>>=1) p += __shfl_xor(p, m);
    if (l == 0) out[b] = 1.f/(1.f + expf(-p));
}

extern "C" void kernel_launch(void* const* d_in, const int* in_sizes, int n_in,
                              void* d_out, int out_size, void* d_ws, size_t ws_size,
                              hipStream_t stream){
    (void)in_sizes; (void)n_in; (void)out_size; (void)ws_size;
    const float* x  = (const float*)d_in[0];
    const float* Wc = (const float*)d_in[1];
    const float* bc = (const float*)d_in[2];
    const float* Wr = (const float*)d_in[3];
    const float* br = (const float*)d_in[4];
    const float* wq = (const float*)d_in[5];
    float* fp   = (float*)d_ws;                  // [64][28][512]
    float* outF = (float*)d_out;

    const int dynC = 112*72*2;           // 16128 B
    (void)hipFuncSetAttribute(reinterpret_cast<const void*>(&k_conv_mfma),
                        hipFuncAttributeMaxDynamicSharedMemorySize, dynC);

    k_conv_mfma<<<64*28,512,dynC,stream>>>(x, Wc, bc, fp);
    k_vqc6<<<64,512,0,stream>>>(wq, fp, Wr, br, outF);
}